// Round 1
// baseline (114.620 us; speedup 1.0000x reference)
//
#include <hip/hip_runtime.h>
#include <stdint.h>

#define NS_ 4096
#define M_  8192
#define D_  256
#define TEMP 0.07f
#define EXP_SCALE 20.61707212818536f   // log2(e)/0.07 : exp(sim/T) = exp2(sim*EXP_SCALE)
#define LN2 0.6931471805599453f

typedef short bf16x8 __attribute__((ext_vector_type(8)));
typedef float f32x4  __attribute__((ext_vector_type(4)));
typedef unsigned short ushortx4 __attribute__((ext_vector_type(4)));

static __device__ inline unsigned short f2bf(float x) {
    unsigned u = __float_as_uint(x);
    u += 0x7fffu + ((u >> 16) & 1u);
    return (unsigned short)(u >> 16);
}

static __device__ inline float cleanf(float v) {
    return __builtin_isfinite(v) ? v : 0.0f;
}

// async 16B global -> LDS (lane-contiguous LDS destination required)
#define LDS_LOAD16(gp, lp) \
    __builtin_amdgcn_global_load_lds((const __attribute__((address_space(1))) uint32_t*)(gp), \
                                     (__attribute__((address_space(3))) uint32_t*)(lp), 16, 0, 0)

// ---------------- Kernel 1: clean + normalize -> bf16 F, fp32 pos[]; zero denom/cnt/out -
// grid = NS_/4, block = 256 (one wave per paired row; 4 row-pairs per block)
__global__ __launch_bounds__(256) void knorm(const float* __restrict__ z1,
                                             const float* __restrict__ z2,
                                             short* __restrict__ F,
                                             float* __restrict__ pos,
                                             float* __restrict__ denom,
                                             int* __restrict__ cnt,
                                             float* __restrict__ out) {
    const int wave = threadIdx.x >> 6;
    const int t    = threadIdx.x & 63;
    const int i    = blockIdx.x * 4 + wave;
    const float4* p1 = (const float4*)(z1 + (size_t)i * D_);
    const float4* p2 = (const float4*)(z2 + (size_t)i * D_);
    float4 a = p1[t], b = p2[t];
    a.x = cleanf(a.x); a.y = cleanf(a.y); a.z = cleanf(a.z); a.w = cleanf(a.w);
    b.x = cleanf(b.x); b.y = cleanf(b.y); b.z = cleanf(b.z); b.w = cleanf(b.w);

    float s1 = a.x*a.x + a.y*a.y + a.z*a.z + a.w*a.w;
    float s2 = b.x*b.x + b.y*b.y + b.z*b.z + b.w*b.w;
    float dp = a.x*b.x + a.y*b.y + a.z*b.z + a.w*b.w;
    #pragma unroll
    for (int m = 1; m < 64; m <<= 1) {
        s1 += __shfl_xor(s1, m);
        s2 += __shfl_xor(s2, m);
        dp += __shfl_xor(dp, m);
    }
    const float inv1 = 1.0f / fmaxf(sqrtf(s1), 1e-12f);
    const float inv2 = 1.0f / fmaxf(sqrtf(s2), 1e-12f);

    ushortx4 o1, o2;
    o1.x = f2bf(a.x * inv1); o1.y = f2bf(a.y * inv1); o1.z = f2bf(a.z * inv1); o1.w = f2bf(a.w * inv1);
    o2.x = f2bf(b.x * inv2); o2.y = f2bf(b.y * inv2); o2.z = f2bf(b.z * inv2); o2.w = f2bf(b.w * inv2);
    ((ushortx4*)(F + (size_t)i * D_))[t]          = o1;
    ((ushortx4*)(F + (size_t)(i + NS_) * D_))[t]  = o2;

    if (t == 0) pos[i] = dp * inv1 * inv2;       // exact fp32 positive sim
    if (t < 2)  denom[i * 2 + t] = 0.0f;         // zero denom (2 per row-pair x 4096)
    if (i == 0 && t < 32) cnt[t] = 0;            // zero rtile counters
    if (i == 0 && t == 0) out[0] = 0.0f;         // zero loss accumulator
}

// ---------------- Kernel 2: fused sim-GEMM + row exp-sums + finishers -------------------
// grid = 512 = 32 rtiles (256 rows) x 16 col-blocks (512 cols). 256 thr / 4 waves.
// Wave w owns 4 row-strips: rows R0 + ch*64 + w*16 (ch=0..3), A-frags K=256 resident.
// Pipeline: 12 staging rounds (4 A-units + 8 B-units, 32 KB each) through a 2x32KB LDS
// double buffer. Counted s_waitcnt vmcnt(8) + raw s_barrier keeps the next unit's 8
// global_load_lds in flight across barriers (never drain vmcnt to 0 in steady state).
__global__ __launch_bounds__(256, 2) void kgemm(const short* __restrict__ F,
                                                float* __restrict__ denom,
                                                int* __restrict__ cnt,
                                                const float* __restrict__ pos,
                                                float* __restrict__ out) {
    __shared__ short Bl[2][64 * 256];   // 2 x 32 KB staging tiles [row][k], 16B chunks swizzled
    __shared__ int lastflag;
    __shared__ float red[4];

    const int rtile = blockIdx.x >> 4;   // 32 rtiles
    const int cq    = blockIdx.x & 15;   // 16 col-blocks
    const int R0 = rtile * 256;
    const int C0 = cq * 512;

    const int tid  = threadIdx.x;
    const int lane = tid & 63;
    const int wave = tid >> 6;
    const int c16  = lane & 15;
    const int quad = lane >> 4;
    const int swz  = c16 & 7;

    // staging source offsets (shorts, relative to 64-row chunk base), XOR-swizzled
    int goff[8];
    #pragma unroll
    for (int r2 = 0; r2 < 8; ++r2) {
        int c    = tid + r2 * 256;
        int row  = c >> 5;
        int kg   = (c & 31) ^ (row & 7);
        goff[r2] = row * D_ + kg * 8;
    }

    const short* baseA = F + (size_t)R0 * D_;
    const short* baseB = F + (size_t)C0 * D_;

    auto STAGE = [&](const short* g, int buf) {
        short* l = &Bl[buf][0];
        #pragma unroll
        for (int r2 = 0; r2 < 8; ++r2)
            LDS_LOAD16(g + goff[r2], l + (tid + r2 * 256) * 8);
    };

    // ---- prologue: stage A-unit 0 into buf0 (nothing has read LDS yet)
    STAGE(baseA, 0);

    // ---- A rounds 0..3: consume A-unit ch from buf(ch&1); prefetch next unit
    bf16x8 afrag[4][8];
    const int arow_l = wave * 16 + c16;
    #pragma unroll
    for (int ch = 0; ch < 4; ++ch) {
        const short* nxt = (ch < 3) ? (baseA + (size_t)(ch + 1) * 64 * D_) : baseB;
        STAGE(nxt, (ch + 1) & 1);
        asm volatile("s_waitcnt vmcnt(8)" ::: "memory");   // unit ch staged; next in flight
        __builtin_amdgcn_s_barrier();
        const short* bp = &Bl[ch & 1][0];
        #pragma unroll
        for (int ks = 0; ks < 8; ++ks)
            afrag[ch][ks] = *(const bf16x8*)(bp + arow_l * 256 +
                                             (((ks * 4 + quad) ^ (arow_l & 7)) * 8));
        asm volatile("s_waitcnt lgkmcnt(0)" ::: "memory"); // reads done before buf reuse
        __builtin_amdgcn_s_barrier();
    }

    float accexp[4][4];
    #pragma unroll
    for (int s = 0; s < 4; ++s)
        #pragma unroll
        for (int r = 0; r < 4; ++r) accexp[s][r] = 0.0f;

    // ---- B rounds 0..7: 64-col groups, double-buffered (round 4+it uses buf(it&1))
    for (int it = 0; it < 8; ++it) {
        if (it < 7) {
            STAGE(baseB + (size_t)(it + 1) * 64 * D_, (it + 1) & 1);
            asm volatile("s_waitcnt vmcnt(8)" ::: "memory");
        } else {
            asm volatile("s_waitcnt vmcnt(0)" ::: "memory");
        }
        __builtin_amdgcn_s_barrier();                      // tile it fully staged
        const short* bp = &Bl[it & 1][0];

        #pragma unroll
        for (int sub = 0; sub < 4; ++sub) {
            const int tc = sub * 16 + c16;     // tile col owned by this lane
            bf16x8 bfrag[8];
            #pragma unroll
            for (int ks = 0; ks < 8; ++ks)
                bfrag[ks] = *(const bf16x8*)(bp + tc * 256 +
                                             (((ks * 4 + quad) ^ swz) * 8));
            f32x4 acc[4];
            #pragma unroll
            for (int s = 0; s < 4; ++s) acc[s] = (f32x4){0.f, 0.f, 0.f, 0.f};
            __builtin_amdgcn_s_setprio(1);
            #pragma unroll
            for (int ks = 0; ks < 8; ++ks)
                #pragma unroll
                for (int s = 0; s < 4; ++s)
                    acc[s] = __builtin_amdgcn_mfma_f32_16x16x32_bf16(
                        afrag[s][ks], bfrag[ks], acc[s], 0, 0, 0);
            __builtin_amdgcn_s_setprio(0);

            const int colbase = C0 + it * 64 + sub * 16;
            #pragma unroll
            for (int s = 0; s < 4; ++s) {
                const int rowbase = R0 + s * 64 + wave * 16;
                if (colbase != rowbase) {            // uniform fast path
                    #pragma unroll
                    for (int r = 0; r < 4; ++r)
                        accexp[s][r] += __builtin_amdgcn_exp2f(acc[s][r] * EXP_SCALE);
                } else {                             // diagonal 16x16 tile
                    #pragma unroll
                    for (int r = 0; r < 4; ++r) {
                        float e = __builtin_amdgcn_exp2f(acc[s][r] * EXP_SCALE);
                        if (c16 == quad * 4 + r) e = 0.0f;
                        accexp[s][r] += e;
                    }
                }
            }
        }
        asm volatile("s_waitcnt lgkmcnt(0)" ::: "memory"); // bfrag reads done before reuse
        __builtin_amdgcn_s_barrier();
    }

    // row sums across the 16 lanes holding each row, one atomic per row
    #pragma unroll
    for (int s = 0; s < 4; ++s)
        #pragma unroll
        for (int r = 0; r < 4; ++r) {
            float v = accexp[s][r];
            v += __shfl_xor(v, 1);
            v += __shfl_xor(v, 2);
            v += __shfl_xor(v, 4);
            v += __shfl_xor(v, 8);
            if (c16 == 0)
                atomicAdd(&denom[R0 + s * 64 + wave * 16 + quad * 4 + r], v);
        }

    // last of 16 blocks per rtile: sum(log(denom[R0..R0+256))) / M -> out (+ pos term)
    __syncthreads();
    if (tid == 0) {
        __threadfence();                              // release our denom adds
        lastflag = (atomicAdd(&cnt[rtile], 1) == 15);
    }
    __syncthreads();
    if (lastflag) {
        __threadfence();                              // acquire others' denom adds
        float v = atomicAdd(&denom[R0 + tid], 0.0f);  // coherent read, 256 rows
        float p = __builtin_amdgcn_logf(v) * (LN2 / (float)M_);
        #pragma unroll
        for (int m = 1; m < 64; m <<= 1) p += __shfl_xor(p, m);
        if (lane == 0) red[wave] = p;
        __syncthreads();
        if (tid == 0) atomicAdd(out, red[0] + red[1] + red[2] + red[3]);
        if (rtile == 0) {                             // pos ready (knorm precedes)
            __syncthreads();                          // protect red reuse
            float sp = 0.0f;
            for (int i = tid; i < NS_; i += 256) sp += pos[i];
            #pragma unroll
            for (int m = 1; m < 64; m <<= 1) sp += __shfl_xor(sp, m);
            if (lane == 0) red[wave] = sp;
            __syncthreads();
            if (tid == 0)
                atomicAdd(out, (red[0] + red[1] + red[2] + red[3]) *
                               (-2.0f / (TEMP * (float)M_)));
        }
    }
}

extern "C" void kernel_launch(void* const* d_in, const int* in_sizes, int n_in,
                              void* d_out, int out_size, void* d_ws, size_t ws_size,
                              hipStream_t stream) {
    const float* z1 = (const float*)d_in[0];
    const float* z2 = (const float*)d_in[1];

    short* F     = (short*)d_ws;                                   // 4 MB
    float* denom = (float*)((char*)d_ws + (size_t)M_ * D_ * 2);    // 32 KB
    int*   cnt   = (int*)(denom + M_);                             // 128 B
    float* pos   = (float*)(cnt + 32);                             // 16 KB
    float* out   = (float*)d_out;

    knorm<<<NS_ / 4, 256, 0, stream>>>(z1, z2, F, pos, denom, cnt, out);
    kgemm<<<512, 256, 0, stream>>>(F, denom, cnt, pos, out);
}

// Round 2
// 111.445 us; speedup vs baseline: 1.0285x; 1.0285x over previous
//
#include <hip/hip_runtime.h>
#include <stdint.h>

#define NS_ 4096
#define M_  8192
#define D_  256
#define TEMP 0.07f
#define EXP_SCALE 20.61707212818536f   // log2(e)/0.07 : exp(sim/T) = exp2(sim*EXP_SCALE)
#define LN2 0.6931471805599453f

typedef short bf16x8 __attribute__((ext_vector_type(8)));
typedef float f32x4  __attribute__((ext_vector_type(4)));
typedef unsigned short ushortx4 __attribute__((ext_vector_type(4)));

static __device__ inline unsigned short f2bf(float x) {
    unsigned u = __float_as_uint(x);
    u += 0x7fffu + ((u >> 16) & 1u);
    return (unsigned short)(u >> 16);
}

static __device__ inline float cleanf(float v) {
    return __builtin_isfinite(v) ? v : 0.0f;
}

// async 16B global -> LDS (lane-contiguous LDS destination required)
#define LDS_LOAD16(gp, lp) \
    __builtin_amdgcn_global_load_lds((const __attribute__((address_space(1))) uint32_t*)(gp), \
                                     (__attribute__((address_space(3))) uint32_t*)(lp), 16, 0, 0)

// ---------------- Kernel 1: clean + normalize -> bf16 F, fp32 pos[]; zero denom/cnt/out -
// grid = NS_/4, block = 256 (one wave per paired row; 4 row-pairs per block)
__global__ __launch_bounds__(256) void knorm(const float* __restrict__ z1,
                                             const float* __restrict__ z2,
                                             short* __restrict__ F,
                                             float* __restrict__ pos,
                                             float* __restrict__ denom,
                                             int* __restrict__ cnt,
                                             float* __restrict__ out) {
    const int wave = threadIdx.x >> 6;
    const int t    = threadIdx.x & 63;
    const int i    = blockIdx.x * 4 + wave;
    const float4* p1 = (const float4*)(z1 + (size_t)i * D_);
    const float4* p2 = (const float4*)(z2 + (size_t)i * D_);
    float4 a = p1[t], b = p2[t];
    a.x = cleanf(a.x); a.y = cleanf(a.y); a.z = cleanf(a.z); a.w = cleanf(a.w);
    b.x = cleanf(b.x); b.y = cleanf(b.y); b.z = cleanf(b.z); b.w = cleanf(b.w);

    float s1 = a.x*a.x + a.y*a.y + a.z*a.z + a.w*a.w;
    float s2 = b.x*b.x + b.y*b.y + b.z*b.z + b.w*b.w;
    float dp = a.x*b.x + a.y*b.y + a.z*b.z + a.w*b.w;
    #pragma unroll
    for (int m = 1; m < 64; m <<= 1) {
        s1 += __shfl_xor(s1, m);
        s2 += __shfl_xor(s2, m);
        dp += __shfl_xor(dp, m);
    }
    const float inv1 = 1.0f / fmaxf(sqrtf(s1), 1e-12f);
    const float inv2 = 1.0f / fmaxf(sqrtf(s2), 1e-12f);

    ushortx4 o1, o2;
    o1.x = f2bf(a.x * inv1); o1.y = f2bf(a.y * inv1); o1.z = f2bf(a.z * inv1); o1.w = f2bf(a.w * inv1);
    o2.x = f2bf(b.x * inv2); o2.y = f2bf(b.y * inv2); o2.z = f2bf(b.z * inv2); o2.w = f2bf(b.w * inv2);
    ((ushortx4*)(F + (size_t)i * D_))[t]          = o1;
    ((ushortx4*)(F + (size_t)(i + NS_) * D_))[t]  = o2;

    if (t == 0) pos[i] = dp * inv1 * inv2;       // exact fp32 positive sim
    if (t < 2)  denom[i * 2 + t] = 0.0f;         // zero denom (2 per row-pair x 4096)
    if (i == 0 && t < 32) cnt[t] = 0;            // zero rtile counters
    if (i == 0 && t == 0) out[0] = 0.0f;         // zero loss accumulator
}

// ---------------- Kernel 2: fused sim-GEMM + row exp-sums + finishers -------------------
// grid = 256 = 32 rtiles (256 rows) x 8 col-blocks (1024 cols). 512 thr / 8 waves,
// 1 block/CU. Wave w owns 32 rows (2 strips of 16): afrag K=256 resident = 64 VGPRs.
// B streams as 16 tiles of 64 cols through a 3x32KB LDS ring, depth-2 prefetch:
// round t reads buf[(t+1)%3]; tile t+2 staged into buf[(t+3)%3] INSIDE the 4 compute
// phases (1 global_load_lds per thread per phase). Entry: s_waitcnt vmcnt(4) + ONE
// s_barrier per round — vmcnt never drains to 0 in steady state (T3+T4). Each phase:
// 8 ds_read_b128 -> 16 MFMA (setprio-wrapped, T5) -> 8 exp2.
__global__ __launch_bounds__(512, 1) void kgemm(const short* __restrict__ F,
                                                float* __restrict__ denom,
                                                int* __restrict__ cnt,
                                                const float* __restrict__ pos,
                                                float* __restrict__ out) {
    __shared__ short Bl[3][64 * 256];   // 3 x 32 KB ring: [row/col][k], 16B granules swizzled
    __shared__ int lastflag;
    __shared__ float red[8];

    const int rtile = blockIdx.x >> 3;   // 32 rtiles
    const int cq    = blockIdx.x & 7;    // 8 col-blocks
    const int R0 = rtile * 256;
    const int C0 = cq * 1024;

    const int tid  = threadIdx.x;
    const int lane = tid & 63;
    const int wave = tid >> 6;
    const int c16  = lane & 15;
    const int quad = lane >> 4;
    const int swz  = c16 & 7;

    // staging source offsets (shorts, relative to 64-row tile base), XOR-swizzled.
    // granule g = tid + r2*512 (2048 granules of 16B per 32KB tile)
    int goff[4];
    #pragma unroll
    for (int r2 = 0; r2 < 4; ++r2) {
        int g   = tid + r2 * 512;
        int row = g >> 5;                 // 32 granules per 256-elem row
        int kg  = (g & 31) ^ (row & 7);
        goff[r2] = row * D_ + kg * 8;
    }

    const short* baseA = F + (size_t)R0 * D_;
    const short* baseB = F + (size_t)C0 * D_;

    short* const bufs0 = &Bl[0][0];
    short* const bufs1 = &Bl[1][0];
    short* const bufs2 = &Bl[2][0];

    // ---- A prologue: 4 chunks of 64 rows through the ring (double-barrier, short).
    // Chunk ch -> buf(ch%3). Wave w reads its rows only during round ch = w>>1.
    bf16x8 afrag[2][8];
    const int mych = wave >> 1;
    const int lrb  = (wave & 1) * 32;    // local row base within my chunk

    {
        #pragma unroll
        for (int r2 = 0; r2 < 4; ++r2)
            LDS_LOAD16(baseA + goff[r2], bufs0 + (tid + r2 * 512) * 8);
    }
    #pragma unroll
    for (int ch = 0; ch < 4; ++ch) {
        const short* nxt = (ch < 3) ? (baseA + (size_t)(ch + 1) * 64 * D_) : baseB;
        short* dst = (ch == 0) ? bufs1 : (ch == 1) ? bufs2 : (ch == 2) ? bufs0 : bufs1;
        #pragma unroll
        for (int r2 = 0; r2 < 4; ++r2)
            LDS_LOAD16(nxt + goff[r2], dst + (tid + r2 * 512) * 8);
        asm volatile("s_waitcnt vmcnt(4)" ::: "memory");   // chunk ch landed; next in flight
        __builtin_amdgcn_s_barrier();
        if (mych == ch) {
            const short* bp = (ch == 0) ? bufs0 : (ch == 1) ? bufs1 : (ch == 2) ? bufs2 : bufs0;
            #pragma unroll
            for (int st = 0; st < 2; ++st) {
                const int row = lrb + st * 16 + c16;       // row&7 == c16&7 == swz
                #pragma unroll
                for (int ks = 0; ks < 8; ++ks)
                    afrag[st][ks] = *(const bf16x8*)(bp + row * 256 +
                                                     (((ks * 4 + quad) ^ swz) * 8));
            }
        }
        asm volatile("s_waitcnt lgkmcnt(0)" ::: "memory"); // reads done before buf reuse
        __builtin_amdgcn_s_barrier();
    }
    // prime B1 -> buf2 (B0 already in buf1 from prologue round ch=3)
    {
        const short* gb = baseB + (size_t)64 * D_;
        #pragma unroll
        for (int r2 = 0; r2 < 4; ++r2)
            LDS_LOAD16(gb + goff[r2], bufs2 + (tid + r2 * 512) * 8);
    }

    float accexp[2][4];
    #pragma unroll
    for (int st = 0; st < 2; ++st)
        #pragma unroll
        for (int r = 0; r < 4; ++r) accexp[st][r] = 0.0f;

    // ring pointers: round t reads pr, next round reads pn, stages t+2 into ps
    short* pr = bufs1;
    short* pn = bufs2;
    short* ps = bufs0;

    // ---- main loop: 16 B-tiles of 64 cols. ONE barrier per round.
    for (int t = 0; t < 16; ++t) {
        if (t < 15) { asm volatile("s_waitcnt vmcnt(4)" ::: "memory"); }
        else        { asm volatile("s_waitcnt vmcnt(0)" ::: "memory"); }
        __builtin_amdgcn_s_barrier();                      // tile t landed on all waves
        const short* gb2 = baseB + (size_t)(t + 2) * 64 * D_;

        #pragma unroll
        for (int sub = 0; sub < 4; ++sub) {
            const int tc = sub * 16 + c16;     // tile col owned by this lane
            bf16x8 bfrag[8];
            #pragma unroll
            for (int ks = 0; ks < 8; ++ks)
                bfrag[ks] = *(const bf16x8*)(pr + tc * 256 +
                                             (((ks * 4 + quad) ^ swz) * 8));
            if (t < 14)                        // stage 1/4 of tile t+2 (write-after-read
                LDS_LOAD16(gb2 + goff[sub], ps + (tid + sub * 512) * 8);  // safe: barrier'd)

            f32x4 acc0 = (f32x4){0.f, 0.f, 0.f, 0.f};
            f32x4 acc1 = (f32x4){0.f, 0.f, 0.f, 0.f};
            __builtin_amdgcn_s_setprio(1);
            #pragma unroll
            for (int ks = 0; ks < 8; ++ks) {
                acc0 = __builtin_amdgcn_mfma_f32_16x16x32_bf16(afrag[0][ks], bfrag[ks], acc0, 0, 0, 0);
                acc1 = __builtin_amdgcn_mfma_f32_16x16x32_bf16(afrag[1][ks], bfrag[ks], acc1, 0, 0, 0);
            }
            __builtin_amdgcn_s_setprio(0);

            const int colbase = C0 + t * 64 + sub * 16;
            #pragma unroll
            for (int st = 0; st < 2; ++st) {
                const f32x4 acc = st ? acc1 : acc0;
                const int rowbase = R0 + wave * 32 + st * 16;
                if (colbase != rowbase) {            // uniform fast path
                    #pragma unroll
                    for (int r = 0; r < 4; ++r)
                        accexp[st][r] += __builtin_amdgcn_exp2f(acc[r] * EXP_SCALE);
                } else {                             // diagonal 16x16 tile
                    #pragma unroll
                    for (int r = 0; r < 4; ++r) {
                        float e = __builtin_amdgcn_exp2f(acc[r] * EXP_SCALE);
                        if (c16 == quad * 4 + r) e = 0.0f;
                        accexp[st][r] += e;
                    }
                }
            }
        }
        // rotate ring
        short* tmp = pr; pr = pn; pn = ps; ps = tmp;
    }

    // row sums across the 16 lanes holding each row, one atomic per row
    #pragma unroll
    for (int st = 0; st < 2; ++st)
        #pragma unroll
        for (int r = 0; r < 4; ++r) {
            float v = accexp[st][r];
            v += __shfl_xor(v, 1);
            v += __shfl_xor(v, 2);
            v += __shfl_xor(v, 4);
            v += __shfl_xor(v, 8);
            if (c16 == 0)
                atomicAdd(&denom[R0 + wave * 32 + st * 16 + quad * 4 + r], v);
        }

    // last of 8 blocks per rtile: sum(log(denom[R0..R0+256))) / M -> out (+ pos term)
    __syncthreads();
    if (tid == 0) {
        __threadfence();                              // release our denom adds
        lastflag = (atomicAdd(&cnt[rtile], 1) == 7);
    }
    __syncthreads();
    if (lastflag) {
        __threadfence();                              // acquire others' denom adds
        float p = 0.0f;
        if (tid < 256) {
            float v = atomicAdd(&denom[R0 + tid], 0.0f);  // coherent read, 256 rows
            p = __builtin_amdgcn_logf(v) * (LN2 / (float)M_);
        }
        #pragma unroll
        for (int m = 1; m < 64; m <<= 1) p += __shfl_xor(p, m);
        if (lane == 0) red[wave] = p;
        __syncthreads();
        if (tid == 0) atomicAdd(out, red[0] + red[1] + red[2] + red[3] +
                                     red[4] + red[5] + red[6] + red[7]);
        if (rtile == 0) {                             // pos ready (knorm precedes)
            __syncthreads();                          // protect red reuse
            float sp = 0.0f;
            for (int i = tid; i < NS_; i += 512) sp += pos[i];
            #pragma unroll
            for (int m = 1; m < 64; m <<= 1) sp += __shfl_xor(sp, m);
            if (lane == 0) red[wave] = sp;
            __syncthreads();
            if (tid == 0)
                atomicAdd(out, (red[0] + red[1] + red[2] + red[3] +
                                red[4] + red[5] + red[6] + red[7]) *
                               (-2.0f / (TEMP * (float)M_)));
        }
    }
}

extern "C" void kernel_launch(void* const* d_in, const int* in_sizes, int n_in,
                              void* d_out, int out_size, void* d_ws, size_t ws_size,
                              hipStream_t stream) {
    const float* z1 = (const float*)d_in[0];
    const float* z2 = (const float*)d_in[1];

    short* F     = (short*)d_ws;                                   // 4 MB
    float* denom = (float*)((char*)d_ws + (size_t)M_ * D_ * 2);    // 32 KB
    int*   cnt   = (int*)(denom + M_);                             // 128 B
    float* pos   = (float*)(cnt + 32);                             // 16 KB
    float* out   = (float*)d_out;

    knorm<<<NS_ / 4, 256, 0, stream>>>(z1, z2, F, pos, denom, cnt, out);
    kgemm<<<256, 512, 0, stream>>>(F, denom, cnt, pos, out);
}